// Round 13
// baseline (213.078 us; speedup 1.0000x reference)
//
#include <hip/hip_runtime.h>

#define GN 4096
#define NCOLS 16384             // N = 128 x * 128 y
#define NROWS 128               // M = 2 ch * 64 z

typedef __attribute__((ext_vector_type(8))) short bf16x8;
typedef __attribute__((ext_vector_type(4))) float f32x4;

// float -> bf16 bits, RNE (harness decode: (u16<<16).view(f32)).
static __device__ __forceinline__ unsigned int f2bf(float f) {
  unsigned int u = __float_as_uint(f);
  unsigned int r = u + 0x7FFFu + ((u >> 16) & 1u);
  return r >> 16;
}
// exact bf16 -> f32 from packed u32 (lo / hi element)
static __device__ __forceinline__ float bflo(unsigned int u) { return __uint_as_float(u << 16); }
static __device__ __forceinline__ float bfhi(unsigned int u) { return __uint_as_float(u & 0xFFFF0000u); }
// pack 2 f32 -> 2 bf16 in one u32 (low = first arg), RNE hardware cvt
static __device__ __forceinline__ unsigned int cvtpk(float lo, float hi) {
  unsigned int ret;
  asm("v_cvt_pk_bf16_f32 %0, %1, %2" : "=v"(ret) : "v"(lo), "v"(hi));
  return ret;
}

// ---------------------------------------------------------------------------
// Tables (bf16, r10-certified): wzT[m][g] (m<64: zr*dre = RE plane, m>=64:
// zr*dimg = IM plane), xrT[x][g], yrT[y][g]; k(g)-contiguous rows.
// ---------------------------------------------------------------------------
__global__ __launch_bounds__(256) void vox_tables(
    const float* __restrict__ pos, const float* __restrict__ cov,
    const float* __restrict__ dre, const float* __restrict__ dimg,
    unsigned short* __restrict__ wzT, unsigned short* __restrict__ xrT,
    unsigned short* __restrict__ yrT) {
  int e = blockIdx.x * 256 + threadIdx.x;
  int g = e & 4095;
  int row = e >> 12;  // 0..383
  if (row < 128) {
    int z = row & 63;
    float c = -1.f + 2.f * (float)z / 63.f;
    float d = c - pos[g * 3 + 0];
    float r = __expf(-0.5f * cov[g * 9 + 0] * d * d);
    wzT[row * 4096 + g] =
        (unsigned short)f2bf(r * (row < 64 ? dre[g] : dimg[g]));
  } else if (row < 256) {
    int x = row - 128;
    float c = -1.f + 2.f * (float)x / 127.f;
    float d = c - pos[g * 3 + 1];
    xrT[x * 4096 + g] =
        (unsigned short)f2bf(__expf(-0.5f * cov[g * 9 + 4] * d * d));
  } else {
    int y = row - 256;
    float c = -1.f + 2.f * (float)y / 127.f;
    float d = c - pos[g * 3 + 2];
    yrT[y * 4096 + g] =
        (unsigned short)f2bf(__expf(-0.5f * cov[g * 9 + 8] * d * d));
  }
}

// ---------------------------------------------------------------------------
// Direct GEMM (r10-certified numerics, restructured for occupancy + fewer
// dispatches): C[128][16384] = wzT x B, B[g][n] = xrT[x,g]*yrT[y,g] built in
// regs (bflo/bfhi exact unpack + f32 mul + v_cvt_pk_bf16_f32). No KSPLIT ->
// each wave owns full K=4096 and stores bf16 output DIRECTLY (no partials,
// no reduce kernel). Grid (128 x, 4 nh) = 512 blocks (2/CU, 2 waves/SIMD vs
// r10's 1). 4 waves/block: wm=(w>>1)*64 (ch plane), wn=(w&1)*16; per-wave
// tile 64m x 16n, acc[4][1]. Per K-step(32): 6 b128 loads, ~28 VALU, 4 MFMA.
// Epilogue: v = z*16384+n; ch=0(re)->flat[2v+1], ch=1(im)->flat[2v]
// (certified layout), byte-exact u16 stores.
// ---------------------------------------------------------------------------
__global__ __launch_bounds__(256) void vox_gemm(
    const unsigned short* __restrict__ wzT,
    const unsigned short* __restrict__ xrT,
    const unsigned short* __restrict__ yrT,
    unsigned short* __restrict__ out16) {
  const int lane = threadIdx.x & 63;
  const int wave = threadIdx.x >> 6;  // 0..3
  const int r  = lane & 15;           // row/col within frag
  const int kg = lane >> 4;           // k-group (8 elems)
  const int wm = (wave >> 1) * 64;    // 0 (RE) | 64 (IM)
  const int ch = wave >> 1;           // 0 = re, 1 = im
  const int x  = blockIdx.x;          // n-block == x coordinate
  const int ncol = blockIdx.y * 32 + (wave & 1) * 16 + r;  // y coordinate

  f32x4 acc[4] = {};

  const unsigned short* Abase = wzT + (size_t)(wm + r) * 4096 + kg * 8;
  const unsigned short* Ybase = yrT + (size_t)ncol * 4096 + kg * 8;
  const unsigned short* Xbase = xrT + (size_t)x * 4096 + kg * 8;

#pragma unroll 2
  for (int kk = 0; kk < GN; kk += 32) {
    uint4 au[4];
#pragma unroll
    for (int i = 0; i < 4; ++i)
      au[i] = *(const uint4*)(Abase + (size_t)i * 16 * 4096 + kk);
    uint4 xu = *(const uint4*)(Xbase + kk);
    uint4 yu = *(const uint4*)(Ybase + kk);
    float xf0 = bflo(xu.x), xf1 = bfhi(xu.x), xf2 = bflo(xu.y), xf3 = bfhi(xu.y);
    float xf4 = bflo(xu.z), xf5 = bfhi(xu.z), xf6 = bflo(xu.w), xf7 = bfhi(xu.w);
    uint4 b;
    b.x = cvtpk(xf0 * bflo(yu.x), xf1 * bfhi(yu.x));
    b.y = cvtpk(xf2 * bflo(yu.y), xf3 * bfhi(yu.y));
    b.z = cvtpk(xf4 * bflo(yu.z), xf5 * bfhi(yu.z));
    b.w = cvtpk(xf6 * bflo(yu.w), xf7 * bfhi(yu.w));
    bf16x8 bv = __builtin_bit_cast(bf16x8, b);
#pragma unroll
    for (int i = 0; i < 4; ++i)
      acc[i] = __builtin_amdgcn_mfma_f32_16x16x32_bf16(
          __builtin_bit_cast(bf16x8, au[i]), bv, acc[i], 0, 0, 0);
  }

  // Epilogue: z = i*16 + kg*4 + q (wm folded into ch), n = x*128 + ncol.
  // flat u16 index: 2*v + (ch ? 0 : 1), v = z*16384 + n.
  const size_t n = (size_t)x * 128 + ncol;
#pragma unroll
  for (int i = 0; i < 4; ++i) {
    int z = i * 16 + kg * 4;
#pragma unroll
    for (int q = 0; q < 4; ++q) {
      size_t v = (size_t)(z + q) * NCOLS + n;
      out16[2 * v + 1 - ch] = (unsigned short)f2bf(acc[i][q]);
    }
  }
}

extern "C" void kernel_launch(void* const* d_in, const int* in_sizes, int n_in,
                              void* d_out, int out_size, void* d_ws, size_t ws_size,
                              hipStream_t stream) {
  const float* pos  = (const float*)d_in[0];  // (G,3) f32
  const float* cov  = (const float*)d_in[1];  // (G,3,3) f32
  const float* dre  = (const float*)d_in[2];  // (G,) f32
  const float* dimg = (const float*)d_in[3];  // (G,) f32

  // ws: bf16 tables only — wzT (1 MB), xrT (1 MB), yrT (1 MB).
  unsigned short* wzT = (unsigned short*)d_ws;
  unsigned short* xrT = wzT + (size_t)128 * 4096;
  unsigned short* yrT = xrT + (size_t)128 * 4096;

  vox_tables<<<6144, 256, 0, stream>>>(pos, cov, dre, dimg, wzT, xrT, yrT);
  vox_gemm<<<dim3(128, 4), 256, 0, stream>>>(wzT, xrT, yrT,
                                             (unsigned short*)d_out);
}

// Round 14
// 123.950 us; speedup vs baseline: 1.7191x; 1.7191x over previous
//
#include <hip/hip_runtime.h>

#define GN 4096
#define BK 64
#define NT (GN / BK)  // 64 k-chunks

typedef __attribute__((ext_vector_type(8))) short bf16x8;
typedef __attribute__((ext_vector_type(4))) float f32x4;

// float -> bf16 bits, RNE (harness decode: (u16<<16).view(f32)).
static __device__ __forceinline__ unsigned int f2bf(float f) {
  unsigned int u = __float_as_uint(f);
  unsigned int r = u + 0x7FFFu + ((u >> 16) & 1u);
  return r >> 16;
}
static __device__ __forceinline__ float bflo(unsigned int u) { return __uint_as_float(u << 16); }
static __device__ __forceinline__ float bfhi(unsigned int u) { return __uint_as_float(u & 0xFFFF0000u); }
static __device__ __forceinline__ unsigned int cvtpk(float lo, float hi) {
  unsigned int ret;
  asm("v_cvt_pk_bf16_f32 %0, %1, %2" : "=v"(ret) : "v"(lo), "v"(hi));
  return ret;
}

// ---------------------------------------------------------------------------
// Tables (bf16): wzT[0..63][g]=zr*dre, [64..127][g]=zr*dimg, xrT[x][g],
// yrT[y][g]. r13 evidence: per-output param gathers made this ~40 us. Fix:
// 16 gaussians' params staged to LDS per block, amortized over all 384 rows.
// Grid 256 blocks x 24 outputs/thread; stores coalesced.
// ---------------------------------------------------------------------------
__global__ __launch_bounds__(256) void vox_tables(
    const float* __restrict__ pos, const float* __restrict__ cov,
    const float* __restrict__ dre, const float* __restrict__ dimg,
    unsigned short* __restrict__ wzT, unsigned short* __restrict__ xrT,
    unsigned short* __restrict__ yrT) {
  __shared__ float P[8][16];  // pz,px,py,cz,cx,cy,dr,di
  const int t = threadIdx.x;
  const int g0 = blockIdx.x * 16;
  if (t < 16) {
    int g = g0 + t;
    P[0][t] = pos[g * 3 + 0];
    P[1][t] = pos[g * 3 + 1];
    P[2][t] = pos[g * 3 + 2];
    P[3][t] = cov[g * 9 + 0];
    P[4][t] = cov[g * 9 + 4];
    P[5][t] = cov[g * 9 + 8];
    P[6][t] = dre[g];
    P[7][t] = dimg[g];
  }
  __syncthreads();
  const int gi = t & 15;
  const int rt = t >> 4;  // 0..15
#pragma unroll
  for (int i = 0; i < 24; ++i) {
    int row = rt + 16 * i;  // 0..383, region uniform across threads per i
    if (row < 128) {
      int z = row & 63;
      float c = -1.f + 2.f * (float)z / 63.f;
      float d = c - P[0][gi];
      float rr = __expf(-0.5f * P[3][gi] * d * d);
      float v = rr * (row < 64 ? P[6][gi] : P[7][gi]);
      wzT[row * 4096 + g0 + gi] = (unsigned short)f2bf(v);
    } else if (row < 256) {
      int xx = row - 128;
      float c = -1.f + 2.f * (float)xx / 127.f;
      float d = c - P[1][gi];
      xrT[xx * 4096 + g0 + gi] =
          (unsigned short)f2bf(__expf(-0.5f * P[4][gi] * d * d));
    } else {
      int yy = row - 256;
      float c = -1.f + 2.f * (float)yy / 127.f;
      float d = c - P[2][gi];
      yrT[yy * 4096 + g0 + gi] =
          (unsigned short)f2bf(__expf(-0.5f * P[5][gi] * d * d));
    }
  }
}

// ---------------------------------------------------------------------------
// LDS-staged GEMM, r13 counters-driven redesign (r13: MfmaUtil 4%, VALU 13%
// -> scattered-VMEM bound; all global access now coalesced, frags from LDS).
// Block = 128m x 64n (one x, half y), FULL K=4096 -> direct certified output
// write (flat[2v]=im, flat[2v+1]=re), no partials. Grid (128,2)=256 blocks.
// LDS dbuf: A=wz[128][64] staged raw; Y'[64][64] = yr*xr generated in regs
// (x folded into Y'). T2 XOR swizzle k8p = k8 ^ (row&7) on write & read
// (conflict-free both sides; A/B k-alignment preserved: both undo per-row).
// 2-phase pipeline: issue next-chunk global loads -> compute current from
// LDS -> gen+write next -> barrier. Per wave/chunk: 12 ds_read_b128 : 16
// MFMA (m97 ratio). Summation order identical to r13-certified -> bitwise
// same result expected (absmax 0.03125).
// ---------------------------------------------------------------------------
__global__ __launch_bounds__(256) void vox_gemm(
    const unsigned short* __restrict__ wzT,
    const unsigned short* __restrict__ xrT,
    const unsigned short* __restrict__ yrT,
    unsigned short* __restrict__ out16) {
  __shared__ __align__(16) unsigned short Asm[2][128 * 64];
  __shared__ __align__(16) unsigned short Ysm[2][64 * 64];
  const int t = threadIdx.x;
  const int lane = t & 63;
  const int wave = t >> 6;   // 0..3
  const int r = lane & 15;
  const int kg = lane >> 4;  // 0..3
  const int ch = wave >> 1;  // 0 = re rows (wz 0..63), 1 = im rows (64..127)
  const int wm = ch * 64;
  const int wn = (wave & 1) * 32;
  const int x = blockIdx.x;
  const int y0 = blockIdx.y * 64;

  // Staging: slot f -> lds row=f>>3, pos k8p=f&7 holds TRUE k8 = k8p^(row&7).
  int aoff[4], yoff[2], xoff[2];
#pragma unroll
  for (int i = 0; i < 4; ++i) {
    int f = t + 256 * i, row = f >> 3;
    aoff[i] = row * 4096 + ((f & 7) ^ (row & 7)) * 8;
  }
#pragma unroll
  for (int i = 0; i < 2; ++i) {
    int f = t + 256 * i, row = f >> 3;
    int k8 = (f & 7) ^ (row & 7);
    yoff[i] = (y0 + row) * 4096 + k8 * 8;
    xoff[i] = x * 4096 + k8 * 8;
  }

  f32x4 acc[4][2] = {};
  uint4 Ar[4], Yr[2], Xr[2];

#define LOADS(kk)                                              \
  {                                                            \
    _Pragma("unroll") for (int i = 0; i < 4; ++i)              \
        Ar[i] = *(const uint4*)(wzT + aoff[i] + (kk));         \
    _Pragma("unroll") for (int i = 0; i < 2; ++i) {            \
      Yr[i] = *(const uint4*)(yrT + yoff[i] + (kk));           \
      Xr[i] = *(const uint4*)(xrT + xoff[i] + (kk));           \
    }                                                          \
  }

#define WRITES(buf)                                                         \
  {                                                                         \
    _Pragma("unroll") for (int i = 0; i < 4; ++i)*(                         \
        uint4*)&Asm[buf][(t + 256 * i) * 8] = Ar[i];                        \
    _Pragma("unroll") for (int i = 0; i < 2; ++i) {                         \
      uint4 b;                                                              \
      b.x = cvtpk(bflo(Yr[i].x) * bflo(Xr[i].x),                            \
                  bfhi(Yr[i].x) * bfhi(Xr[i].x));                           \
      b.y = cvtpk(bflo(Yr[i].y) * bflo(Xr[i].y),                            \
                  bfhi(Yr[i].y) * bfhi(Xr[i].y));                           \
      b.z = cvtpk(bflo(Yr[i].z) * bflo(Xr[i].z),                            \
                  bfhi(Yr[i].z) * bfhi(Xr[i].z));                           \
      b.w = cvtpk(bflo(Yr[i].w) * bflo(Xr[i].w),                            \
                  bfhi(Yr[i].w) * bfhi(Xr[i].w));                           \
      *(uint4*)&Ysm[buf][(t + 256 * i) * 8] = b;                            \
    }                                                                       \
  }

#define COMPUTE(buf)                                                        \
  {                                                                         \
    _Pragma("unroll") for (int ks = 0; ks < 2; ++ks) {                      \
      const int kidx = ((ks * 4 + kg) ^ (r & 7)) * 8;                       \
      uint4 au[4], yv[2];                                                   \
      _Pragma("unroll") for (int i = 0; i < 4; ++i) au[i] =                 \
          *(const uint4*)&Asm[buf][(wm + i * 16 + r) * 64 + kidx];          \
      _Pragma("unroll") for (int j = 0; j < 2; ++j) yv[j] =                 \
          *(const uint4*)&Ysm[buf][(wn + j * 16 + r) * 64 + kidx];          \
      _Pragma("unroll") for (int i = 0; i < 4; ++i)                         \
          _Pragma("unroll") for (int j = 0; j < 2; ++j) acc[i][j] =         \
              __builtin_amdgcn_mfma_f32_16x16x32_bf16(                      \
                  __builtin_bit_cast(bf16x8, au[i]),                        \
                  __builtin_bit_cast(bf16x8, yv[j]), acc[i][j], 0, 0, 0);   \
    }                                                                       \
  }

  // Prologue: stage chunk 0.
  LOADS(0);
  WRITES(0);
  __syncthreads();

  int cb = 0;
  for (int tc = 0; tc < NT - 1; ++tc) {
    LOADS((tc + 1) * BK);   // issue early: HBM/L2 latency hides under MFMA
    COMPUTE(cb);
    WRITES(cb ^ 1);         // waits on loads via data-dep (vmcnt)
    __syncthreads();
    cb ^= 1;
  }
  COMPUTE(cb);

  // Epilogue (r13-certified mapping): z = i*16+kg*4+q, n = x*128+y0+wn+j*16+r,
  // v = z*16384+n; re (ch=0) -> flat[2v+1], im (ch=1) -> flat[2v].
#pragma unroll
  for (int i = 0; i < 4; ++i) {
#pragma unroll
    for (int j = 0; j < 2; ++j) {
      int n = x * 128 + y0 + wn + j * 16 + r;
#pragma unroll
      for (int q = 0; q < 4; ++q) {
        int z = i * 16 + kg * 4 + q;
        size_t v = (size_t)z * 16384 + n;
        out16[2 * v + 1 - ch] = (unsigned short)f2bf(acc[i][j][q]);
      }
    }
  }
}

extern "C" void kernel_launch(void* const* d_in, const int* in_sizes, int n_in,
                              void* d_out, int out_size, void* d_ws, size_t ws_size,
                              hipStream_t stream) {
  const float* pos  = (const float*)d_in[0];  // (G,3) f32
  const float* cov  = (const float*)d_in[1];  // (G,3,3) f32
  const float* dre  = (const float*)d_in[2];  // (G,) f32
  const float* dimg = (const float*)d_in[3];  // (G,) f32

  // ws: bf16 tables only — wzT/xrT/yrT (1 MB each).
  unsigned short* wzT = (unsigned short*)d_ws;
  unsigned short* xrT = wzT + (size_t)128 * 4096;
  unsigned short* yrT = xrT + (size_t)128 * 4096;

  vox_tables<<<256, 256, 0, stream>>>(pos, cov, dre, dimg, wzT, xrT, yrT);
  vox_gemm<<<dim3(128, 2), 256, 0, stream>>>(wzT, xrT, yrT,
                                             (unsigned short*)d_out);
}

// Round 15
// 107.676 us; speedup vs baseline: 1.9789x; 1.1511x over previous
//
#include <hip/hip_runtime.h>

#define GN 4096
#define BK 64
#define NT (GN / BK)  // 64 k-chunks

typedef __attribute__((ext_vector_type(8))) short bf16x8;
typedef __attribute__((ext_vector_type(4))) float f32x4;

// float -> bf16 bits, RNE (harness decode: (u16<<16).view(f32)).
static __device__ __forceinline__ unsigned int f2bf(float f) {
  unsigned int u = __float_as_uint(f);
  unsigned int r = u + 0x7FFFu + ((u >> 16) & 1u);
  return r >> 16;
}
static __device__ __forceinline__ float bflo(unsigned int u) { return __uint_as_float(u << 16); }
static __device__ __forceinline__ float bfhi(unsigned int u) { return __uint_as_float(u & 0xFFFF0000u); }
static __device__ __forceinline__ unsigned int cvtpk(float lo, float hi) {
  unsigned int ret;
  asm("v_cvt_pk_bf16_f32 %0, %1, %2" : "=v"(ret) : "v"(lo), "v"(hi));
  return ret;
}

// ---------------------------------------------------------------------------
// Tables (bf16): wzT[0..63][g]=zr*dre, [64..127][g]=zr*dimg, xrT[x][g],
// yrT[y][g]. REVERTED to the r10/r13 high-occupancy form: one output per
// thread, 6144 blocks (24 blocks/CU), coalesced 128B stores per wave.
// (r14's 256-block "staged" version was itself 1-wave/SIMD latency-bound
// and likely ~40us of the unexplained residual.)
// ---------------------------------------------------------------------------
__global__ __launch_bounds__(256) void vox_tables(
    const float* __restrict__ pos, const float* __restrict__ cov,
    const float* __restrict__ dre, const float* __restrict__ dimg,
    unsigned short* __restrict__ wzT, unsigned short* __restrict__ xrT,
    unsigned short* __restrict__ yrT) {
  int e = blockIdx.x * 256 + threadIdx.x;
  int g = e & 4095;
  int row = e >> 12;  // 0..383
  if (row < 128) {
    int z = row & 63;
    float c = -1.f + 2.f * (float)z / 63.f;
    float d = c - pos[g * 3 + 0];
    float r = __expf(-0.5f * cov[g * 9 + 0] * d * d);
    wzT[row * 4096 + g] =
        (unsigned short)f2bf(r * (row < 64 ? dre[g] : dimg[g]));
  } else if (row < 256) {
    int x = row - 128;
    float c = -1.f + 2.f * (float)x / 127.f;
    float d = c - pos[g * 3 + 1];
    xrT[x * 4096 + g] =
        (unsigned short)f2bf(__expf(-0.5f * cov[g * 9 + 4] * d * d));
  } else {
    int y = row - 256;
    float c = -1.f + 2.f * (float)y / 127.f;
    float d = c - pos[g * 3 + 2];
    yrT[y * 4096 + g] =
        (unsigned short)f2bf(__expf(-0.5f * cov[g * 9 + 8] * d * d));
  }
}

// ---------------------------------------------------------------------------
// LDS-staged GEMM, r14 structure with 8 WAVES (512 threads): r14 counters
// (MfmaUtil 9.9%, VALU 18%, Occupancy 10% = 1 wave/SIMD) said latency-bound,
// not BW-bound -> double the waves, keep everything else bit-identical.
// Block = 128m x 64n, full K=4096, grid (128,2)=256 blocks = 1 block/CU,
// 8 waves = 2/SIMD. Per wave: 64m x 16n (ch = wave>>2 selects re/im plane,
// wn = (wave&3)*16). LDS dbuf 48KB: A=wz[128][64] raw, Y'[64][64]=yr*xr
// built in regs during staging. T2 XOR swizzle k8p=k8^(row&7) write & read
// (2-way max = free, r14 measured 0 conflicts). Per wave/chunk: 10
// ds_read_b128 : 8 MFMA. Summation order identical to r13/r14-certified.
// ---------------------------------------------------------------------------
__global__ __launch_bounds__(512) void vox_gemm(
    const unsigned short* __restrict__ wzT,
    const unsigned short* __restrict__ xrT,
    const unsigned short* __restrict__ yrT,
    unsigned short* __restrict__ out16) {
  __shared__ __align__(16) unsigned short Asm[2][128 * 64];
  __shared__ __align__(16) unsigned short Ysm[2][64 * 64];
  const int t = threadIdx.x;   // 0..511
  const int lane = t & 63;
  const int wave = t >> 6;     // 0..7
  const int r = lane & 15;
  const int kg = lane >> 4;    // 0..3
  const int ch = wave >> 2;    // 0 = re rows (wz 0..63), 1 = im rows (64..127)
  const int wm = ch * 64;
  const int wn = (wave & 3) * 16;
  const int x = blockIdx.x;
  const int y0 = blockIdx.y * 64;

  // Staging: slot f -> lds row=f>>3, pos k8p=f&7 holds TRUE k8 = k8p^(row&7).
  int aoff[2], yoff, xoff;
#pragma unroll
  for (int i = 0; i < 2; ++i) {
    int f = t + 512 * i, row = f >> 3;
    aoff[i] = row * 4096 + ((f & 7) ^ (row & 7)) * 8;
  }
  {
    int row = t >> 3;
    int k8 = (t & 7) ^ (row & 7);
    yoff = (y0 + row) * 4096 + k8 * 8;
    xoff = x * 4096 + k8 * 8;
  }

  f32x4 acc[4] = {};
  uint4 Ar[2], Yr, Xr;

#define LOADS(kk)                                              \
  {                                                            \
    _Pragma("unroll") for (int i = 0; i < 2; ++i)              \
        Ar[i] = *(const uint4*)(wzT + aoff[i] + (kk));         \
    Yr = *(const uint4*)(yrT + yoff + (kk));                   \
    Xr = *(const uint4*)(xrT + xoff + (kk));                   \
  }

#define WRITES(buf)                                                         \
  {                                                                         \
    _Pragma("unroll") for (int i = 0; i < 2; ++i)*(                         \
        uint4*)&Asm[buf][(t + 512 * i) * 8] = Ar[i];                        \
    uint4 b;                                                                \
    b.x = cvtpk(bflo(Yr.x) * bflo(Xr.x), bfhi(Yr.x) * bfhi(Xr.x));          \
    b.y = cvtpk(bflo(Yr.y) * bflo(Xr.y), bfhi(Yr.y) * bfhi(Xr.y));          \
    b.z = cvtpk(bflo(Yr.z) * bflo(Xr.z), bfhi(Yr.z) * bfhi(Xr.z));          \
    b.w = cvtpk(bflo(Yr.w) * bflo(Xr.w), bfhi(Yr.w) * bfhi(Xr.w));          \
    *(uint4*)&Ysm[buf][t * 8] = b;                                          \
  }

#define COMPUTE(buf)                                                        \
  {                                                                         \
    _Pragma("unroll") for (int ks = 0; ks < 2; ++ks) {                      \
      const int kidx = ((ks * 4 + kg) ^ (r & 7)) * 8;                       \
      uint4 au[4], yv;                                                      \
      _Pragma("unroll") for (int i = 0; i < 4; ++i) au[i] =                 \
          *(const uint4*)&Asm[buf][(wm + i * 16 + r) * 64 + kidx];          \
      yv = *(const uint4*)&Ysm[buf][(wn + r) * 64 + kidx];                  \
      _Pragma("unroll") for (int i = 0; i < 4; ++i) acc[i] =                \
          __builtin_amdgcn_mfma_f32_16x16x32_bf16(                          \
              __builtin_bit_cast(bf16x8, au[i]),                            \
              __builtin_bit_cast(bf16x8, yv), acc[i], 0, 0, 0);             \
    }                                                                       \
  }

  // Prologue: stage chunk 0.
  LOADS(0);
  WRITES(0);
  __syncthreads();

  int cb = 0;
  for (int tc = 0; tc < NT - 1; ++tc) {
    LOADS((tc + 1) * BK);   // issue early: L2 latency hides under compute
    COMPUTE(cb);
    WRITES(cb ^ 1);         // waits on loads via data-dep (vmcnt)
    __syncthreads();
    cb ^= 1;
  }
  COMPUTE(cb);

  // Epilogue (certified mapping): z = i*16+kg*4+q, n = x*128+y0+wn+r,
  // v = z*16384+n; re (ch=0) -> flat[2v+1], im (ch=1) -> flat[2v].
  const int n = x * 128 + y0 + wn + r;
#pragma unroll
  for (int i = 0; i < 4; ++i) {
#pragma unroll
    for (int q = 0; q < 4; ++q) {
      int z = i * 16 + kg * 4 + q;
      size_t v = (size_t)z * 16384 + n;
      out16[2 * v + 1 - ch] = (unsigned short)f2bf(acc[i][q]);
    }
  }
}

extern "C" void kernel_launch(void* const* d_in, const int* in_sizes, int n_in,
                              void* d_out, int out_size, void* d_ws, size_t ws_size,
                              hipStream_t stream) {
  const float* pos  = (const float*)d_in[0];  // (G,3) f32
  const float* cov  = (const float*)d_in[1];  // (G,3,3) f32
  const float* dre  = (const float*)d_in[2];  // (G,) f32
  const float* dimg = (const float*)d_in[3];  // (G,) f32

  // ws: bf16 tables only — wzT/xrT/yrT (1 MB each).
  unsigned short* wzT = (unsigned short*)d_ws;
  unsigned short* xrT = wzT + (size_t)128 * 4096;
  unsigned short* yrT = xrT + (size_t)128 * 4096;

  vox_tables<<<6144, 256, 0, stream>>>(pos, cov, dre, dimg, wzT, xrT, yrT);
  vox_gemm<<<dim3(128, 2), 512, 0, stream>>>(wzT, xrT, yrT,
                                             (unsigned short*)d_out);
}